// Round 3
// baseline (587.651 us; speedup 1.0000x reference)
//
#include <hip/hip_runtime.h>

// out (176, 192, 56, 56) fp32:
//   out[:, :64]  = x (176, 64, 56, 56)              (straight copy)
//   out[:, 64:]  = y (176, 128, 28, 28) NN-upsample x2
// HBM floor: read 212 MB + write 424 MB = 636 MB -> ~101 us @ 6.3 TB/s.
//
// Two uniform halves in one grid:
//   threads [0, NXV):      copy one float4 of x -> out
//   threads [NXV, NXV+NYV): read one float2 of y, write two float4s (rows 2h, 2h+1)
// y read exactly once; all traffic nontemporal (pure streaming, no reuse).
// NOTE: __builtin_nontemporal_* requires clang ext_vector types, not HIP's
// float4 class -> use vf4/vf2 typedefs.

typedef float vf4 __attribute__((ext_vector_type(4)));
typedef float vf2 __attribute__((ext_vector_type(2)));

#define NXV 8830976   // 176*64*56*14  (x float4 count)
#define NYV 8830976   // 176*128*28*14 (y float2 count)
// NXV+NYV = 17,661,952 = 68,992 * 256 exactly (no tail check needed)

__global__ __launch_bounds__(256) void upcat_kernel(
    const float* __restrict__ x,
    const float* __restrict__ y,
    float* __restrict__ out)
{
    int i = blockIdx.x * blockDim.x + threadIdx.x;

    if (i < NXV) {
        // ---- copy half: x(b, c, h, w) -> out(b, c, h, w) ----
        int r  = i / 14;            // x row id = b*3584 + cr,  cr = c*56 + h
        int j  = i - r * 14;        // float4 slot in row
        int b  = r / 3584;          // 3584 = 64*56
        int cr = r - b * 3584;

        vf4 v = __builtin_nontemporal_load((const vf4*)(x + r * 56 + 4 * j));
        // out linear = ((b*192 + c)*56 + h)*56 + w = b*602112 + cr*56 + 4j
        __builtin_nontemporal_store(v, (vf4*)(out + b * 602112 + cr * 56 + 4 * j));
    } else {
        // ---- upsample half: y(b, c2, h2, w2) -> out rows 2*h2 and 2*h2+1 ----
        int k   = i - NXV;
        int ry  = k / 14;           // y row id = (b*128 + c2)*28 + h2
        int j   = k - ry * 14;      // float2 slot in y row (covers 4 out floats)

        vf2 u = __builtin_nontemporal_load((const vf2*)(y + ry * 28 + 2 * j));

        int b   = ry / 3584;        // 3584 = 128*28
        int cr2 = ry - b * 3584;    // c2*28 + h2
        int c2  = cr2 / 28;
        int h2  = cr2 - c2 * 28;

        vf4 v;
        v.x = u.x; v.y = u.x; v.z = u.y; v.w = u.y;
        int orow = (b * 192 + 64 + c2) * 56 + 2 * h2;
        __builtin_nontemporal_store(v, (vf4*)(out + orow * 56 + 4 * j));
        __builtin_nontemporal_store(v, (vf4*)(out + (orow + 1) * 56 + 4 * j));
    }
}

extern "C" void kernel_launch(void* const* d_in, const int* in_sizes, int n_in,
                              void* d_out, int out_size, void* d_ws, size_t ws_size,
                              hipStream_t stream) {
    const float* x = (const float*)d_in[0];
    const float* y = (const float*)d_in[1];
    float* out = (float*)d_out;

    upcat_kernel<<<(NXV + NYV) / 256, 256, 0, stream>>>(x, y, out);
}